// Round 16
// baseline (3513.030 us; speedup 1.0000x reference)
//
#include <hip/hip_runtime.h>
#include <hip/hip_bf16.h>

#define S 2048
#define NEGV -10000.0f

typedef unsigned long long ull;
typedef unsigned int uint4v __attribute__((ext_vector_type(4)));

__device__ __forceinline__ float fsig(float x) {
  return 1.0f / (1.0f + __expf(-x));
}
__device__ __forceinline__ float ftanh(float x) {
  float a = fabsf(x);
  float e = __expf(-2.0f * a);
  float r = (1.0f - e) / (1.0f + e);
  return copysignf(r, x);
}

// ---------------- init: seed h0 (stamp 1) + clear all flags/counters ----------
__global__ void init_k(const float* __restrict__ h0, ull* __restrict__ hbuf,
                       int* __restrict__ flags) {
  int b = blockIdx.x, u = threadIdx.x;
  if (b < 2) {                         // b = dir
    ull pk = (1ULL << 32) | (ull)__float_as_uint(h0[b * 512 + u]);
    __hip_atomic_store(&hbuf[b * 1024 + u], pk, __ATOMIC_RELAXED, __HIP_MEMORY_SCOPE_AGENT);
    __hip_atomic_store(&hbuf[b * 1024 + 512 + u], 0ULL, __ATOMIC_RELAXED, __HIP_MEMORY_SCOPE_AGENT);
  } else {                             // blocks 2..9 clear flags[0..4095]
    __hip_atomic_store(&flags[(b - 2) * 512 + u], 0, __ATOMIC_RELAXED, __HIP_MEMORY_SCOPE_AGENT);
  }
}

// ---------------- map composition for backtrack: r[i] = a[b[i]] ----------------
__device__ __forceinline__ ull compose_map(ull a, ull b) {
  ull r = 0;
  #pragma unroll
  for (int i = 0; i < 16; ++i) {
    int bi = (int)((b >> (4 * i)) & 15);
    int ai = (int)((a >> (4 * bi)) & 15);
    r |= (ull)ai << (4 * i);
  }
  return r;
}

// flags layout: [0..2047] xg tile flags; [2049] feats-done counter;
// [2064 + c*16] chunk-republish counters (c = 0..31, 64B apart).
//
// FUSED: blocks 0..127 LSTM (+ per-chunk republish; block 0 also Viterbi),
//        blocks 128..255 GEMM tiles then CHUNK FEATS (overlapped with chain).
__global__ __launch_bounds__(256) void fused_k(
    const int* __restrict__ sent, const float* __restrict__ emb,
    const float* __restrict__ Wih_f, const float* __restrict__ Wih_b,
    const float* __restrict__ bih_f, const float* __restrict__ bhh_f,
    const float* __restrict__ bih_b, const float* __restrict__ bhh_b,
    const float* __restrict__ Whh_f, const float* __restrict__ Whh_b,
    const float* __restrict__ c0,
    const float* __restrict__ Wout, const float* __restrict__ bout,
    const float* __restrict__ trans,
    float* __restrict__ xg,            // [S][4096]
    ull* __restrict__ hbuf,            // [2 dir][2 slot][512]
    float* __restrict__ hs_cat,        // [S][1024]
    float* __restrict__ feats,         // [S][16]
    int* __restrict__ flags,
    float* __restrict__ out)           // [1 + S]
{
  __shared__ __align__(16) float smem[9232];
  const int t = threadIdx.x;

  if (blockIdx.x >= 128) {
    // ================= GEMM worker: 16 tiles, then chunk feats =================
    {
      float* Asm = smem;                 // [64][36]
      float* Bsm = smem + 2304;          // [32][68]
      int*   sidx = (int*)(smem + 4480); // [64]
      const int tm = t >> 4, tn = t & 15;
      const int lr = t >> 2, lkq = t & 3;

      for (int i = 0; i < 16; ++i) {
        const int T = (blockIdx.x - 128) + 128 * i;   // priority rank
        const int byo = T >> 6, bxo = T & 63;
        const int by = (byo & 1) ? (31 - (byo >> 1)) : (byo >> 1);
        const int bx = (bxo & 1) ? (32 + (bxo >> 1)) : (bxo >> 1);
        const int n0 = bx * 64, m0 = by * 64;

        const float* W = (n0 < 2048) ? (Wih_f + (size_t)n0 * 1024)
                                     : (Wih_b + (size_t)(n0 - 2048) * 1024);
        __syncthreads();
        if (t < 64) sidx[t] = sent[m0 + t];
        __syncthreads();

        float acc[4][4] = {};
        for (int k0 = 0; k0 < 1024; k0 += 32) {
          const float* ap = emb + (size_t)sidx[lr] * 1024 + k0 + lkq * 8;
          float4 a0 = *(const float4*)ap;
          float4 a1 = *(const float4*)(ap + 4);
          const float* bp = W + (size_t)lr * 1024 + k0 + lkq * 8;
          float4 b0 = *(const float4*)bp;
          float4 b1 = *(const float4*)(bp + 4);
          __syncthreads();
          *(float4*)&Asm[lr * 36 + lkq * 8]     = a0;
          *(float4*)&Asm[lr * 36 + lkq * 8 + 4] = a1;
          {
            const float* bb0 = (const float*)&b0;
            const float* bb1 = (const float*)&b1;
            #pragma unroll
            for (int j = 0; j < 4; ++j) Bsm[(lkq * 8 + j) * 68 + lr] = bb0[j];
            #pragma unroll
            for (int j = 0; j < 4; ++j) Bsm[(lkq * 8 + 4 + j) * 68 + lr] = bb1[j];
          }
          __syncthreads();
          #pragma unroll
          for (int kk = 0; kk < 32; ++kk) {
            float a0_ = Asm[(tm * 4 + 0) * 36 + kk];
            float a1_ = Asm[(tm * 4 + 1) * 36 + kk];
            float a2_ = Asm[(tm * 4 + 2) * 36 + kk];
            float a3_ = Asm[(tm * 4 + 3) * 36 + kk];
            float4 bv = *(const float4*)&Bsm[kk * 68 + tn * 4];
            acc[0][0] = fmaf(a0_, bv.x, acc[0][0]); acc[0][1] = fmaf(a0_, bv.y, acc[0][1]);
            acc[0][2] = fmaf(a0_, bv.z, acc[0][2]); acc[0][3] = fmaf(a0_, bv.w, acc[0][3]);
            acc[1][0] = fmaf(a1_, bv.x, acc[1][0]); acc[1][1] = fmaf(a1_, bv.y, acc[1][1]);
            acc[1][2] = fmaf(a1_, bv.z, acc[1][2]); acc[1][3] = fmaf(a1_, bv.w, acc[1][3]);
            acc[2][0] = fmaf(a2_, bv.x, acc[2][0]); acc[2][1] = fmaf(a2_, bv.y, acc[2][1]);
            acc[2][2] = fmaf(a2_, bv.z, acc[2][2]); acc[2][3] = fmaf(a2_, bv.w, acc[2][3]);
            acc[3][0] = fmaf(a3_, bv.x, acc[3][0]); acc[3][1] = fmaf(a3_, bv.y, acc[3][1]);
            acc[3][2] = fmaf(a3_, bv.z, acc[3][2]); acc[3][3] = fmaf(a3_, bv.w, acc[3][3]);
          }
        }

        const float* bi = (n0 < 2048) ? bih_f : bih_b;
        const float* bh = (n0 < 2048) ? bhh_f : bhh_b;
        const int nb = (n0 < 2048) ? n0 : (n0 - 2048);
        #pragma unroll
        for (int ii = 0; ii < 4; ++ii) {
          int m = m0 + tm * 4 + ii;
          #pragma unroll
          for (int j = 0; j < 4; ++j) {
            int nn = tn * 4 + j;
            float bias = bi[nb + nn] + bh[nb + nn];
            __hip_atomic_store(&xg[(size_t)m * 4096 + n0 + nn], acc[ii][j] + bias,
                               __ATOMIC_RELAXED, __HIP_MEMORY_SCOPE_AGENT);
          }
        }
        asm volatile("s_waitcnt vmcnt(0)" ::: "memory");
        __syncthreads();
        if (t == 0)
          __hip_atomic_store(&flags[by * 64 + bx], 1, __ATOMIC_RELAXED, __HIP_MEMORY_SCOPE_AGENT);
      }
    }

    // ---- chunk feats (overlapped with the lstm chain) ----
    {
      const int gb = blockIdx.x - 128;     // 0..127
      const int rank = gb >> 2, sub = gb & 3;
      const int c = (rank & 1) ? (16 + (rank >> 1)) : (15 - (rank >> 1));  // middle-out

      if (t == 0) {
        while (__hip_atomic_load(&flags[2064 + c * 16], __ATOMIC_RELAXED,
                                 __HIP_MEMORY_SCOPE_AGENT) != 128)
          __builtin_amdgcn_s_sleep(32);
      }
      __syncthreads();

      const int l = t & 63;
      const int wv4 = t >> 6;              // wave 0..3
      const int j = l & 15, q = l >> 4;    // q = 0..3 (256-float chunks)
      #pragma unroll
      for (int r = 0; r < 4; ++r) {
        const int tpos = c * 64 + sub * 16 + wv4 * 4 + r;
        const float* h = hs_cat + (size_t)tpos * 1024 + q * 256;
        const float* wp = Wout + (size_t)j * 1024 + q * 256;
        float s = 0.f;
        #pragma unroll 8
        for (int i = 0; i < 256; i += 4) {
          float4 hv = *(const float4*)(h + i);
          float4 ww = *(const float4*)(wp + i);
          s = fmaf(hv.x, ww.x, s); s = fmaf(hv.y, ww.y, s);
          s = fmaf(hv.z, ww.z, s); s = fmaf(hv.w, ww.w, s);
        }
        s += __shfl_xor(s, 16);
        s += __shfl_xor(s, 32);
        if (q == 0)
          __hip_atomic_store(&feats[tpos * 16 + j], s + bout[j],
                             __ATOMIC_RELAXED, __HIP_MEMORY_SCOPE_AGENT);
      }
      __syncthreads();   // drains WT feats stores (pre-barrier vmcnt(0))
      if (t == 0)
        __hip_atomic_fetch_add(&flags[2049], 1, __ATOMIC_RELAXED, __HIP_MEMORY_SCOPE_AGENT);
    }
    return;
  }

  // ================= LSTM role (R10 chain + per-chunk republish) =================
  {
    const int w = blockIdx.x;
    const int dir = w & 1;
    const int wid = w >> 1;              // 0..63
    const int rr = t >> 3;               // row-in-wg 0..31
    const int seg = t & 7;               // 0..7
    const int g  = rr & 3;               // gate 0..3 (i,f,g,o)
    const int ul = rr >> 2;              // local unit 0..7
    const int unit = wid * 8 + ul;       // 0..511
    const int grow = g * 512 + unit;     // global Whh row
    const int bxf  = dir * 32 + g * 8 + (wid >> 3);   // flag column for this row's xg

    float (*h_lds)[544] = (float(*)[544])smem;        // [2][544]

    const float* Whh = dir ? Whh_b : Whh_f;
    float wreg[64];
    {
      const float* src = Whh + (size_t)grow * 512 + seg * 64;
      #pragma unroll
      for (int j = 0; j < 16; ++j) {
        float4 v = *(const float4*)(src + j * 4);
        wreg[4 * j + 0] = v.x; wreg[4 * j + 1] = v.y;
        wreg[4 * j + 2] = v.z; wreg[4 * j + 3] = v.w;
      }
    }

    ull* hb = hbuf + dir * 1024;
    float c_reg = c0[dir * 512 + unit];  // meaningful on g==0 lanes

    const int u0 = t * 2;
    const int wchunk = u0 >> 6, wpos = u0 & 63;

    float xg_a = 0.0f, xg_b = 0.0f;
    if (seg == 0) {
      int by0 = dir ? 31 : 0;
      while (__hip_atomic_load(&flags[by0 * 64 + bxf], __ATOMIC_RELAXED,
                               __HIP_MEMORY_SCOPE_AGENT) != 1)
        __builtin_amdgcn_s_sleep(8);
      int r0 = dir ? (S - 1) : 0;
      int r1 = dir ? (S - 2) : 1;
      xg_a = __hip_atomic_load(&xg[(size_t)r0 * 4096 + dir * 2048 + grow],
                               __ATOMIC_RELAXED, __HIP_MEMORY_SCOPE_AGENT);
      xg_b = __hip_atomic_load(&xg[(size_t)r1 * 4096 + dir * 2048 + grow],
                               __ATOMIC_RELAXED, __HIP_MEMORY_SCOPE_AGENT);
    }

    #define LSTM_STEP(K, XG_REG)                                                  \
    {                                                                             \
      const int k = (K);                                                          \
      float xgv = XG_REG;                                                         \
      if (seg == 0 && k + 2 < S) {       /* prefetch row k+2 into same reg */     \
        int rowk = dir ? (S - 3 - k) : (k + 2);                                   \
        if ((rowk & 63) == (dir ? 63 : 0)) {   /* entering new 64-row block */    \
          int byn = rowk >> 6;                                                    \
          while (__hip_atomic_load(&flags[byn * 64 + bxf], __ATOMIC_RELAXED,      \
                                   __HIP_MEMORY_SCOPE_AGENT) != 1)                \
            __builtin_amdgcn_s_sleep(8);                                          \
        }                                                                         \
        XG_REG = __hip_atomic_load(&xg[(size_t)rowk * 4096 + dir * 2048 + grow],  \
                                   __ATOMIC_RELAXED, __HIP_MEMORY_SCOPE_AGENT);   \
      }                                                                           \
      /* poll h_k: stamp k+1 in slot k&1; 16B coherent load, sleep backoff */     \
      {                                                                           \
        ull* src = hb + (k & 1) * 512 + u0;                                       \
        const unsigned want = (unsigned)(k + 1);                                  \
        uint4v v;                                                                 \
        asm volatile("global_load_dwordx4 %0, %1, off sc0 sc1"                    \
                     : "=v"(v) : "v"(src) : "memory");                            \
        asm volatile("s_waitcnt vmcnt(0)" ::: "memory");                          \
        while (v.y != want || v.w != want) {                                      \
          __builtin_amdgcn_s_sleep(1);                                            \
          asm volatile("global_load_dwordx4 %0, %1, off sc0 sc1"                  \
                       : "=v"(v) : "v"(src) : "memory");                          \
          asm volatile("s_waitcnt vmcnt(0)" ::: "memory");                        \
        }                                                                         \
        float* dst = &h_lds[k & 1][wchunk * 68 + wpos];                           \
        dst[0] = __uint_as_float(v.x);                                            \
        dst[1] = __uint_as_float(v.z);                                            \
      }                                                                           \
      __syncthreads();                                                            \
      /* 64-wide partial dot of row `grow` */                                     \
      const float* hl = &h_lds[k & 1][0];                                         \
      float p0 = 0.f, p1 = 0.f, p2 = 0.f, p3 = 0.f;                               \
      const float4* h4 = (const float4*)(hl + seg * 68);                          \
      _Pragma("unroll")                                                           \
      for (int j = 0; j < 16; ++j) {                                              \
        float4 hv = h4[j];                                                        \
        p0 = fmaf(wreg[4 * j + 0], hv.x, p0);                                     \
        p1 = fmaf(wreg[4 * j + 1], hv.y, p1);                                     \
        p2 = fmaf(wreg[4 * j + 2], hv.z, p2);                                     \
        p3 = fmaf(wreg[4 * j + 3], hv.w, p3);                                     \
      }                                                                           \
      float p = (p0 + p1) + (p2 + p3) + xgv;                                      \
      p += __shfl_xor(p, 1);                                                      \
      p += __shfl_xor(p, 2);                                                      \
      p += __shfl_xor(p, 4);                                                      \
      float gb_ = __shfl_xor(p, 8);      /* gate g^1 */                           \
      float gc_ = __shfl_xor(p, 16);     /* gate g^2 */                           \
      float gd_ = __shfl_xor(gb_, 16);   /* gate g^3 */                           \
      if (g == 0) {                                                               \
        float iv = fsig(p), fv = fsig(gb_), ov = fsig(gd_);                       \
        float gv = ftanh(gc_);                                                    \
        c_reg = fv * c_reg + iv * gv;                                             \
        float hv = ov * ftanh(c_reg);                                             \
        if (seg == 0) {                                                           \
          ull pk = ((ull)(unsigned)(k + 2) << 32) | (ull)__float_as_uint(hv);     \
          __hip_atomic_store(&hb[((k + 1) & 1) * 512 + unit], pk,                 \
                             __ATOMIC_RELAXED, __HIP_MEMORY_SCOPE_AGENT);         \
          int orig = dir ? (S - 1 - k) : k;                                       \
          hs_cat[(size_t)orig * 1024 + dir * 512 + unit] = hv;  /* plain: L2 ack */\
        }                                                                         \
      }                                                                           \
    }

    for (int kk = 0; kk < S; kk += 2) {
      LSTM_STEP(kk, xg_a);
      LSTM_STEP(kk + 1, xg_b);

      if ((kk & 63) == 62) {
        // chunk boundary: rows of chunk c fully written by this WG.
        const int c = dir ? ((S - 2 - kk) >> 6) : ((kk + 1) >> 6);
        __syncthreads();   // drain this block's plain hs stores (incl. row kk+1)
        {
          const int base2 = dir * 512 + wid * 8;
          const int i2 = t * 2;
          const int rl = i2 >> 3, u2 = i2 & 7;
          float* p = &hs_cat[(size_t)(c * 64 + rl) * 1024 + base2 + u2];
          float v0 = p[0], v1 = p[1];           // own-L2 hits
          __hip_atomic_store(p,     v0, __ATOMIC_RELAXED, __HIP_MEMORY_SCOPE_AGENT);
          __hip_atomic_store(p + 1, v1, __ATOMIC_RELAXED, __HIP_MEMORY_SCOPE_AGENT);
        }
        __syncthreads();   // drain WT republish stores (pre-barrier vmcnt(0))
        if (t == 0)
          __hip_atomic_fetch_add(&flags[2064 + c * 16], 1,
                                 __ATOMIC_RELAXED, __HIP_MEMORY_SCOPE_AGENT);
      }
    }
    #undef LSTM_STEP
  }

  if (blockIdx.x != 0) return;

  // ================= Viterbi (block 0): wait feats, max-plus matrix scan =========
  {
    if (t == 0) {
      while (__hip_atomic_load(&flags[2049], __ATOMIC_RELAXED,
                               __HIP_MEMORY_SCOPE_AGENT) != 128)
        __builtin_amdgcn_s_sleep(8);
    }
    __syncthreads();

    float* P_ls  = smem;               // [32][16][16] -> later bp bytes [2048][16]
    float* vb    = smem + 8192;        // [32][16]  boundary vectors
    float* Trows = smem + 8704;        // [16][16]  T row-major
    float* tslot = smem + 9216;        // [term, ti]

    if (t < 256) Trows[t] = trans[t];
    __syncthreads();

    const int G = t >> 4, r = t & 15;

    // ---- V1: compose chunk matrices P_c (lane r holds row r of P) ----
    {
      float Tcol[16];
      #pragma unroll
      for (int j = 0; j < 16; ++j) Tcol[j] = Trows[j * 16 + r];

      for (int cc = 0; cc < 2; ++cc) {
        const int c = G * 2 + cc, t0 = c * 64;
        float P[16];
        {
          const float4* fr = (const float4*)&feats[t0 * 16];
          float4 fA = fr[0], fB = fr[1], fC = fr[2], fD = fr[3];
          float ff[16];
          ff[0]=fA.x; ff[1]=fA.y; ff[2]=fA.z; ff[3]=fA.w;
          ff[4]=fB.x; ff[5]=fB.y; ff[6]=fB.z; ff[7]=fB.w;
          ff[8]=fC.x; ff[9]=fC.y; ff[10]=fC.z; ff[11]=fC.w;
          ff[12]=fD.x; ff[13]=fD.y; ff[14]=fD.z; ff[15]=fD.w;
          #pragma unroll
          for (int j = 0; j < 16; ++j) P[j] = Tcol[j] + ff[j];
        }
        for (int tt = t0 + 1; tt < t0 + 64; ++tt) {
          const float4* fr = (const float4*)&feats[tt * 16];
          float4 fA = fr[0], fB = fr[1], fC = fr[2], fD = fr[3];
          float ff[16];
          ff[0]=fA.x; ff[1]=fA.y; ff[2]=fA.z; ff[3]=fA.w;
          ff[4]=fB.x; ff[5]=fB.y; ff[6]=fB.z; ff[7]=fB.w;
          ff[8]=fC.x; ff[9]=fC.y; ff[10]=fC.z; ff[11]=fC.w;
          ff[12]=fD.x; ff[13]=fD.y; ff[14]=fD.z; ff[15]=fD.w;
          float Q[16];
          #pragma unroll
          for (int j = 0; j < 16; ++j) {
            const float4 Ta = *(const float4*)&Trows[j * 16 + 0];
            const float4 Tb = *(const float4*)&Trows[j * 16 + 4];
            const float4 Tc2 = *(const float4*)&Trows[j * 16 + 8];
            const float4 Td = *(const float4*)&Trows[j * 16 + 12];
            float m0 = fmaxf(P[0]  + Ta.x,  P[1]  + Ta.y);
            float m1 = fmaxf(P[2]  + Ta.z,  P[3]  + Ta.w);
            float m2 = fmaxf(P[4]  + Tb.x,  P[5]  + Tb.y);
            float m3 = fmaxf(P[6]  + Tb.z,  P[7]  + Tb.w);
            float m4 = fmaxf(P[8]  + Tc2.x, P[9]  + Tc2.y);
            float m5 = fmaxf(P[10] + Tc2.z, P[11] + Tc2.w);
            float m6 = fmaxf(P[12] + Td.x,  P[13] + Td.y);
            float m7 = fmaxf(P[14] + Td.z,  P[15] + Td.w);
            float m = fmaxf(fmaxf(fmaxf(m0, m1), fmaxf(m2, m3)),
                            fmaxf(fmaxf(m4, m5), fmaxf(m6, m7)));
            Q[j] = m + ff[j];
          }
          #pragma unroll
          for (int j = 0; j < 16; ++j) P[j] = Q[j];
        }
        #pragma unroll
        for (int j = 0; j < 16; ++j) P_ls[c * 256 + r * 16 + j] = P[j];
      }
    }
    __syncthreads();

    // ---- V2: boundary scan (lanes 0..15 of wave 0) ----
    if (t < 16) {
      float m = (t == 0) ? 0.0f : NEGV;   // v[-1]
      for (int c = 0; c < 32; ++c) {
        float vv[16];
        #pragma unroll
        for (int i = 0; i < 16; ++i) vv[i] = __shfl(m, i, 16);
        float nm = vv[0] + P_ls[c * 256 + 0 * 16 + t];
        #pragma unroll
        for (int i = 1; i < 16; ++i)
          nm = fmaxf(nm, vv[i] + P_ls[c * 256 + i * 16 + t]);
        vb[c * 16 + t] = nm;
        m = nm;
      }
    }
    __syncthreads();

    // ---- V3: replay chunks, write bp bytes into dead P region ----
    {
      unsigned char* bpB = (unsigned char*)P_ls;   // [2048][16] bytes = 32KB
      float Trow[16];
      #pragma unroll
      for (int k2 = 0; k2 < 16; ++k2) Trow[k2] = Trows[r * 16 + k2];

      for (int cc = 0; cc < 2; ++cc) {
        const int c = G * 2 + cc, t0 = c * 64;
        float vcur = (c == 0) ? ((r == 0) ? 0.0f : NEGV) : vb[(c - 1) * 16 + r];
        float fnext = feats[t0 * 16 + r];
        for (int tt = t0; tt < t0 + 64; ++tt) {
          float f = fnext;
          if (tt + 1 < t0 + 64) fnext = feats[(tt + 1) * 16 + r];
          float vv[16];
          #pragma unroll
          for (int i = 0; i < 16; ++i) vv[i] = __shfl(vcur, i, 16);
          float m = vv[0] + Trow[0]; int mi = 0;
          #pragma unroll
          for (int i = 1; i < 16; ++i) {
            float s2 = vv[i] + Trow[i];
            if (s2 > m) { m = s2; mi = i; }
          }
          vcur = m + f;
          bpB[tt * 16 + r] = (unsigned char)mi;
        }
      }
    }
    __syncthreads();

    // ---- V4a: terminal argmax (first-index ties) ----
    if (t < 16) {
      float term = vb[31 * 16 + t] + trans[16 + t];   // STOP row = 1
      int ti = t;
      #pragma unroll
      for (int mask = 1; mask <= 8; mask <<= 1) {
        float om = __shfl_xor(term, mask);
        int omi = __shfl_xor(ti, mask);
        if (om > term || (om == term && omi < ti)) { term = om; ti = omi; }
      }
      if (t == 0) { tslot[0] = term; tslot[1] = __int_as_float(ti); }
    }
    __syncthreads();

    // ---- V4b: map-suffix-scan backtrack (wave 0), maps from bp bytes ----
    if (t < 64) {
      const unsigned char* bpB = (const unsigned char*)P_ls;
      const int l = t;
      ull M = 0;
      {
        const int tb = 32 * l + 31;
        #pragma unroll
        for (int j = 0; j < 16; ++j)
          M |= (ull)(bpB[tb * 16 + j] & 15) << (4 * j);
      }
      for (int i = 30; i >= 0; --i) {
        const int ta = 32 * l + i;
        ull Mn = 0;
        #pragma unroll
        for (int j = 0; j < 16; ++j) {
          int idx = (int)((M >> (4 * j)) & 15);
          Mn |= (ull)(bpB[ta * 16 + idx] & 15) << (4 * j);
        }
        M = Mn;
      }
      ull Sm = M;
      #pragma unroll
      for (int d = 1; d < 64; d <<= 1) {
        ull o = __shfl_down(Sm, d);
        if (l + d < 64) Sm = compose_map(Sm, o);
      }
      ull Gm = __shfl_down(Sm, 1);
      if (l == 63) Gm = 0xFEDCBA9876543210ULL;   // identity

      int ti = __float_as_int(tslot[1]);
      int cur = (int)((Gm >> (4 * ti)) & 15);    // tag @ t = 32l+31
      for (int i = 31; i >= 1; --i) {
        int tt2 = 32 * l + i;
        out[1 + tt2] = (float)cur;
        cur = bpB[tt2 * 16 + cur] & 15;          // tag @ tt2-1
      }
      out[1 + 32 * l] = (float)cur;
      if (l == 0) out[0] = tslot[0];
    }
  }
}

extern "C" void kernel_launch(void* const* d_in, const int* in_sizes, int n_in,
                              void* d_out, int out_size, void* d_ws, size_t ws_size,
                              hipStream_t stream) {
  const int*   sent  = (const int*)d_in[0];
  const float* emb   = (const float*)d_in[1];
  const float* Wih_f = (const float*)d_in[2];
  const float* Whh_f = (const float*)d_in[3];
  const float* bih_f = (const float*)d_in[4];
  const float* bhh_f = (const float*)d_in[5];
  const float* Wih_b = (const float*)d_in[6];
  const float* Whh_b = (const float*)d_in[7];
  const float* bih_b = (const float*)d_in[8];
  const float* bhh_b = (const float*)d_in[9];
  const float* h0    = (const float*)d_in[10];
  const float* c0    = (const float*)d_in[11];
  const float* Wout  = (const float*)d_in[12];
  const float* bout  = (const float*)d_in[13];
  const float* trans = (const float*)d_in[14];
  float* out = (float*)d_out;

  // workspace layout
  char* ws = (char*)d_ws;
  float* xg     = (float*)(ws);                         // 2048*4096*4 = 32 MiB
  float* hs_cat = (float*)(ws + 33554432);              // 2048*1024*4 = 8 MiB
  float* feats  = (float*)(ws + 41943040);              // 2048*16*4 = 128 KiB
  ull*   hbuf   = (ull*)  (ws + 42074112);              // 2*2*512*8 = 16 KiB
  int*   flags  = (int*)  (ws + 42090496);              // 4096 ints = 16 KiB

  init_k<<<10, 512, 0, stream>>>(h0, hbuf, flags);
  fused_k<<<256, 256, 0, stream>>>(sent, emb, Wih_f, Wih_b, bih_f, bhh_f,
                                   bih_b, bhh_b, Whh_f, Whh_b, c0, Wout, bout,
                                   trans, xg, hbuf, hs_cat, feats, flags, out);
}

// Round 17
// 3472.374 us; speedup vs baseline: 1.0117x; 1.0117x over previous
//
#include <hip/hip_runtime.h>
#include <hip/hip_bf16.h>

#define S 2048
#define NEGV -10000.0f

typedef unsigned long long ull;
typedef unsigned int uint4v __attribute__((ext_vector_type(4)));

__device__ __forceinline__ float fsig(float x) {
  return 1.0f / (1.0f + __expf(-x));
}
__device__ __forceinline__ float ftanh(float x) {
  float a = fabsf(x);
  float e = __expf(-2.0f * a);
  float r = (1.0f - e) / (1.0f + e);
  return copysignf(r, x);
}

// ---------------- init: seed h0 (stamp 1) + clear tile flags + 2 counters ----------
__global__ void init_k(const float* __restrict__ h0, ull* __restrict__ hbuf,
                       int* __restrict__ flags) {
  int b = blockIdx.x, u = threadIdx.x;
  if (b < 2) {                         // b = dir
    ull pk = (1ULL << 32) | (ull)__float_as_uint(h0[b * 512 + u]);
    __hip_atomic_store(&hbuf[b * 1024 + u], pk, __ATOMIC_RELAXED, __HIP_MEMORY_SCOPE_AGENT);
    __hip_atomic_store(&hbuf[b * 1024 + 512 + u], 0ULL, __ATOMIC_RELAXED, __HIP_MEMORY_SCOPE_AGENT);
  } else {
    __hip_atomic_store(&flags[(b - 2) * 512 + u], 0, __ATOMIC_RELAXED, __HIP_MEMORY_SCOPE_AGENT);
    if (b == 2 && u < 2)
      __hip_atomic_store(&flags[2048 + u], 0, __ATOMIC_RELAXED, __HIP_MEMORY_SCOPE_AGENT);
  }
}

// ---------------- map composition for backtrack: r[i] = a[b[i]] ----------------
__device__ __forceinline__ ull compose_map(ull a, ull b) {
  ull r = 0;
  #pragma unroll
  for (int i = 0; i < 16; ++i) {
    int bi = (int)((b >> (4 * i)) & 15);
    int ai = (int)((a >> (4 * bi)) & 15);
    r |= (ull)ai << (4 * i);
  }
  return r;
}

// ---------------- FUSED: 0..127 LSTM(+feats+viterbi), 128..255 GEMM (exit) ---------
// LSTM chain = R10 (proven): single 16B sc0sc1 poll + sleep(1), publish-first,
// plain hs_cat store; bulk republish for cross-XCD visibility; feats 16 rows/block.
// Max-plus MATRIX-SCAN Viterbi in block 0:
//  V1: 16 lane-groups compose 32 chunk matrices P_c (64 steps each) in regs
//  V2: 16-lane boundary scan v_c = v_{c-1} (x) P_c
//  V3: groups replay chunks from boundaries, exact per-step order, bp bytes
//      written into the (dead) P region of LDS
//  V4: map-suffix-scan backtrack, maps built from bp bytes
__global__ __launch_bounds__(256) void fused_k(
    const int* __restrict__ sent, const float* __restrict__ emb,
    const float* __restrict__ Wih_f, const float* __restrict__ Wih_b,
    const float* __restrict__ bih_f, const float* __restrict__ bhh_f,
    const float* __restrict__ bih_b, const float* __restrict__ bhh_b,
    const float* __restrict__ Whh_f, const float* __restrict__ Whh_b,
    const float* __restrict__ c0,
    const float* __restrict__ Wout, const float* __restrict__ bout,
    const float* __restrict__ trans,
    float* __restrict__ xg,            // [S][4096]
    ull* __restrict__ hbuf,            // [2 dir][2 slot][512]
    float* __restrict__ hs_cat,        // [S][1024]
    float* __restrict__ feats,         // [S][16]
    int* __restrict__ flags,           // [2048 tile flags][2 counters]
    float* __restrict__ out)           // [1 + S]
{
  // union: gemm 4544f | lstm 1088f | viterbi 9218f (P/bp 8192 + vb 512 + T 256 + pad + 2)
  __shared__ __align__(16) float smem[9232];
  const int t = threadIdx.x;

  if (blockIdx.x >= 128) {
    // ================= persistent GEMM worker (exits when done) =================
    float* Asm = smem;                 // [64][36]
    float* Bsm = smem + 2304;          // [32][68]
    int*   sidx = (int*)(smem + 4480); // [64]
    const int tm = t >> 4, tn = t & 15;
    const int lr = t >> 2, lkq = t & 3;

    for (int i = 0; i < 16; ++i) {
      const int T = (blockIdx.x - 128) + 128 * i;   // priority rank
      const int byo = T >> 6, bxo = T & 63;
      const int by = (byo & 1) ? (31 - (byo >> 1)) : (byo >> 1);
      const int bx = (bxo & 1) ? (32 + (bxo >> 1)) : (bxo >> 1);
      const int n0 = bx * 64, m0 = by * 64;

      const float* W = (n0 < 2048) ? (Wih_f + (size_t)n0 * 1024)
                                   : (Wih_b + (size_t)(n0 - 2048) * 1024);
      __syncthreads();
      if (t < 64) sidx[t] = sent[m0 + t];
      __syncthreads();

      float acc[4][4] = {};
      for (int k0 = 0; k0 < 1024; k0 += 32) {
        const float* ap = emb + (size_t)sidx[lr] * 1024 + k0 + lkq * 8;
        float4 a0 = *(const float4*)ap;
        float4 a1 = *(const float4*)(ap + 4);
        const float* bp = W + (size_t)lr * 1024 + k0 + lkq * 8;
        float4 b0 = *(const float4*)bp;
        float4 b1 = *(const float4*)(bp + 4);
        __syncthreads();
        *(float4*)&Asm[lr * 36 + lkq * 8]     = a0;
        *(float4*)&Asm[lr * 36 + lkq * 8 + 4] = a1;
        {
          const float* bb0 = (const float*)&b0;
          const float* bb1 = (const float*)&b1;
          #pragma unroll
          for (int j = 0; j < 4; ++j) Bsm[(lkq * 8 + j) * 68 + lr] = bb0[j];
          #pragma unroll
          for (int j = 0; j < 4; ++j) Bsm[(lkq * 8 + 4 + j) * 68 + lr] = bb1[j];
        }
        __syncthreads();
        #pragma unroll
        for (int kk = 0; kk < 32; ++kk) {
          float a0_ = Asm[(tm * 4 + 0) * 36 + kk];
          float a1_ = Asm[(tm * 4 + 1) * 36 + kk];
          float a2_ = Asm[(tm * 4 + 2) * 36 + kk];
          float a3_ = Asm[(tm * 4 + 3) * 36 + kk];
          float4 bv = *(const float4*)&Bsm[kk * 68 + tn * 4];
          acc[0][0] = fmaf(a0_, bv.x, acc[0][0]); acc[0][1] = fmaf(a0_, bv.y, acc[0][1]);
          acc[0][2] = fmaf(a0_, bv.z, acc[0][2]); acc[0][3] = fmaf(a0_, bv.w, acc[0][3]);
          acc[1][0] = fmaf(a1_, bv.x, acc[1][0]); acc[1][1] = fmaf(a1_, bv.y, acc[1][1]);
          acc[1][2] = fmaf(a1_, bv.z, acc[1][2]); acc[1][3] = fmaf(a1_, bv.w, acc[1][3]);
          acc[2][0] = fmaf(a2_, bv.x, acc[2][0]); acc[2][1] = fmaf(a2_, bv.y, acc[2][1]);
          acc[2][2] = fmaf(a2_, bv.z, acc[2][2]); acc[2][3] = fmaf(a2_, bv.w, acc[2][3]);
          acc[3][0] = fmaf(a3_, bv.x, acc[3][0]); acc[3][1] = fmaf(a3_, bv.y, acc[3][1]);
          acc[3][2] = fmaf(a3_, bv.z, acc[3][2]); acc[3][3] = fmaf(a3_, bv.w, acc[3][3]);
        }
      }

      const float* bi = (n0 < 2048) ? bih_f : bih_b;
      const float* bh = (n0 < 2048) ? bhh_f : bhh_b;
      const int nb = (n0 < 2048) ? n0 : (n0 - 2048);
      #pragma unroll
      for (int ii = 0; ii < 4; ++ii) {
        int m = m0 + tm * 4 + ii;
        #pragma unroll
        for (int j = 0; j < 4; ++j) {
          int nn = tn * 4 + j;
          float bias = bi[nb + nn] + bh[nb + nn];
          __hip_atomic_store(&xg[(size_t)m * 4096 + n0 + nn], acc[ii][j] + bias,
                             __ATOMIC_RELAXED, __HIP_MEMORY_SCOPE_AGENT);
        }
      }
      asm volatile("s_waitcnt vmcnt(0)" ::: "memory");
      __syncthreads();
      if (t == 0)
        __hip_atomic_store(&flags[by * 64 + bx], 1, __ATOMIC_RELAXED, __HIP_MEMORY_SCOPE_AGENT);
    }
    return;   // no spinning during the chain
  }

  // ================= LSTM role (R10 chain, plain hs_cat store) =================
  {
    const int w = blockIdx.x;
    const int dir = w & 1;
    const int wid = w >> 1;              // 0..63
    const int rr = t >> 3;               // row-in-wg 0..31
    const int seg = t & 7;               // 0..7
    const int g  = rr & 3;               // gate 0..3 (i,f,g,o)
    const int ul = rr >> 2;              // local unit 0..7
    const int unit = wid * 8 + ul;       // 0..511
    const int grow = g * 512 + unit;     // global Whh row
    const int bxf  = dir * 32 + g * 8 + (wid >> 3);   // flag column for this row's xg

    float (*h_lds)[544] = (float(*)[544])smem;        // [2][544]

    const float* Whh = dir ? Whh_b : Whh_f;
    float wreg[64];
    {
      const float* src = Whh + (size_t)grow * 512 + seg * 64;
      #pragma unroll
      for (int j = 0; j < 16; ++j) {
        float4 v = *(const float4*)(src + j * 4);
        wreg[4 * j + 0] = v.x; wreg[4 * j + 1] = v.y;
        wreg[4 * j + 2] = v.z; wreg[4 * j + 3] = v.w;
      }
    }

    ull* hb = hbuf + dir * 1024;
    float c_reg = c0[dir * 512 + unit];  // meaningful on g==0 lanes

    const int u0 = t * 2;
    const int wchunk = u0 >> 6, wpos = u0 & 63;

    float xg_a = 0.0f, xg_b = 0.0f;
    if (seg == 0) {
      int by0 = dir ? 31 : 0;
      while (__hip_atomic_load(&flags[by0 * 64 + bxf], __ATOMIC_RELAXED,
                               __HIP_MEMORY_SCOPE_AGENT) != 1)
        __builtin_amdgcn_s_sleep(8);
      int r0 = dir ? (S - 1) : 0;
      int r1 = dir ? (S - 2) : 1;
      xg_a = __hip_atomic_load(&xg[(size_t)r0 * 4096 + dir * 2048 + grow],
                               __ATOMIC_RELAXED, __HIP_MEMORY_SCOPE_AGENT);
      xg_b = __hip_atomic_load(&xg[(size_t)r1 * 4096 + dir * 2048 + grow],
                               __ATOMIC_RELAXED, __HIP_MEMORY_SCOPE_AGENT);
    }

    #define LSTM_STEP(K, XG_REG)                                                  \
    {                                                                             \
      const int k = (K);                                                          \
      float xgv = XG_REG;                                                         \
      if (seg == 0 && k + 2 < S) {       /* prefetch row k+2 into same reg */     \
        int rowk = dir ? (S - 3 - k) : (k + 2);                                   \
        if ((rowk & 63) == (dir ? 63 : 0)) {   /* entering new 64-row block */    \
          int byn = rowk >> 6;                                                    \
          while (__hip_atomic_load(&flags[byn * 64 + bxf], __ATOMIC_RELAXED,      \
                                   __HIP_MEMORY_SCOPE_AGENT) != 1)                \
            __builtin_amdgcn_s_sleep(8);                                          \
        }                                                                         \
        XG_REG = __hip_atomic_load(&xg[(size_t)rowk * 4096 + dir * 2048 + grow],  \
                                   __ATOMIC_RELAXED, __HIP_MEMORY_SCOPE_AGENT);   \
      }                                                                           \
      /* poll h_k: stamp k+1 in slot k&1; 16B coherent load, sleep backoff */     \
      {                                                                           \
        ull* src = hb + (k & 1) * 512 + u0;                                       \
        const unsigned want = (unsigned)(k + 1);                                  \
        uint4v v;                                                                 \
        asm volatile("global_load_dwordx4 %0, %1, off sc0 sc1"                    \
                     : "=v"(v) : "v"(src) : "memory");                            \
        asm volatile("s_waitcnt vmcnt(0)" ::: "memory");                          \
        while (v.y != want || v.w != want) {                                      \
          __builtin_amdgcn_s_sleep(1);                                            \
          asm volatile("global_load_dwordx4 %0, %1, off sc0 sc1"                  \
                       : "=v"(v) : "v"(src) : "memory");                          \
          asm volatile("s_waitcnt vmcnt(0)" ::: "memory");                        \
        }                                                                         \
        float* dst = &h_lds[k & 1][wchunk * 68 + wpos];                           \
        dst[0] = __uint_as_float(v.x);                                            \
        dst[1] = __uint_as_float(v.z);                                            \
      }                                                                           \
      __syncthreads();                                                            \
      /* 64-wide partial dot of row `grow` */                                     \
      const float* hl = &h_lds[k & 1][0];                                         \
      float p0 = 0.f, p1 = 0.f, p2 = 0.f, p3 = 0.f;                               \
      const float4* h4 = (const float4*)(hl + seg * 68);                          \
      _Pragma("unroll")                                                           \
      for (int j = 0; j < 16; ++j) {                                              \
        float4 hv = h4[j];                                                        \
        p0 = fmaf(wreg[4 * j + 0], hv.x, p0);                                     \
        p1 = fmaf(wreg[4 * j + 1], hv.y, p1);                                     \
        p2 = fmaf(wreg[4 * j + 2], hv.z, p2);                                     \
        p3 = fmaf(wreg[4 * j + 3], hv.w, p3);                                     \
      }                                                                           \
      float p = (p0 + p1) + (p2 + p3) + xgv;                                      \
      p += __shfl_xor(p, 1);                                                      \
      p += __shfl_xor(p, 2);                                                      \
      p += __shfl_xor(p, 4);                                                      \
      float gb_ = __shfl_xor(p, 8);      /* gate g^1 */                           \
      float gc_ = __shfl_xor(p, 16);     /* gate g^2 */                           \
      float gd_ = __shfl_xor(gb_, 16);   /* gate g^3 */                           \
      if (g == 0) {                                                               \
        float iv = fsig(p), fv = fsig(gb_), ov = fsig(gd_);                       \
        float gv = ftanh(gc_);                                                    \
        c_reg = fv * c_reg + iv * gv;                                             \
        float hv = ov * ftanh(c_reg);                                             \
        if (seg == 0) {                                                           \
          ull pk = ((ull)(unsigned)(k + 2) << 32) | (ull)__float_as_uint(hv);     \
          __hip_atomic_store(&hb[((k + 1) & 1) * 512 + unit], pk,                 \
                             __ATOMIC_RELAXED, __HIP_MEMORY_SCOPE_AGENT);         \
          int orig = dir ? (S - 1 - k) : k;                                       \
          hs_cat[(size_t)orig * 1024 + dir * 512 + unit] = hv;  /* plain: L2 ack */\
        }                                                                         \
      }                                                                           \
    }

    for (int kk = 0; kk < S; kk += 2) {
      LSTM_STEP(kk, xg_a);
      LSTM_STEP(kk + 1, xg_b);
    }
    #undef LSTM_STEP

    // drain per-step stores (own L2), then bulk-republish this block's 64KB
    // hs_cat slice write-through for cross-XCD visibility (pipelined).
    asm volatile("s_waitcnt vmcnt(0)" ::: "memory");
    __syncthreads();
    {
      const int base = dir * 512 + wid * 8;
      for (int i = t; i < 16384; i += 256) {
        const int row = i >> 3, u2 = i & 7;
        float* p = &hs_cat[(size_t)row * 1024 + base + u2];
        float v = *p;                      // hits own XCD L2 (dirty line)
        __hip_atomic_store(p, v, __ATOMIC_RELAXED, __HIP_MEMORY_SCOPE_AGENT);
      }
    }
    asm volatile("s_waitcnt vmcnt(0)" ::: "memory");
    __syncthreads();
    if (t == 0)
      __hip_atomic_fetch_add(&flags[2048], 1, __ATOMIC_RELAXED, __HIP_MEMORY_SCOPE_AGENT);
  }

  // ================= feats phase (128 lstm blocks, 16 rows each) =================
  if (t == 0) {
    while (__hip_atomic_load(&flags[2048], __ATOMIC_RELAXED,
                             __HIP_MEMORY_SCOPE_AGENT) != 128)
      __builtin_amdgcn_s_sleep(8);     // chain-synchronized arrival: short spin
  }
  __syncthreads();
  {
    const int l = t & 63;
    const int wv4 = t >> 6;              // wave 0..3
    const int j = l & 15, q = l >> 4;    // q = 0..3 (256-float chunks)
    #pragma unroll
    for (int r = 0; r < 4; ++r) {
      const int tpos = blockIdx.x * 16 + wv4 * 4 + r;
      const float* h = hs_cat + (size_t)tpos * 1024 + q * 256;
      const float* wp = Wout + (size_t)j * 1024 + q * 256;
      float s = 0.f;
      #pragma unroll 8
      for (int i = 0; i < 256; i += 4) {
        float4 hv = *(const float4*)(h + i);
        float4 ww = *(const float4*)(wp + i);
        s = fmaf(hv.x, ww.x, s); s = fmaf(hv.y, ww.y, s);
        s = fmaf(hv.z, ww.z, s); s = fmaf(hv.w, ww.w, s);
      }
      s += __shfl_xor(s, 16);
      s += __shfl_xor(s, 32);
      if (q == 0)
        __hip_atomic_store(&feats[tpos * 16 + j], s + bout[j],
                           __ATOMIC_RELAXED, __HIP_MEMORY_SCOPE_AGENT);
    }
  }
  asm volatile("s_waitcnt vmcnt(0)" ::: "memory");
  __syncthreads();
  if (t == 0)
    __hip_atomic_fetch_add(&flags[2049], 1, __ATOMIC_RELAXED, __HIP_MEMORY_SCOPE_AGENT);

  // ================= Viterbi (block 0): max-plus matrix scan =================
  if (blockIdx.x == 0) {
    if (t == 0) {
      while (__hip_atomic_load(&flags[2049], __ATOMIC_RELAXED,
                               __HIP_MEMORY_SCOPE_AGENT) != 128)
        __builtin_amdgcn_s_sleep(8);
    }
    __syncthreads();

    float* P_ls  = smem;               // [32][16][16] -> later reused as bp bytes [2048][16]
    float* vb    = smem + 8192;        // [32][16]  boundary vectors
    float* Trows = smem + 8704;        // [16][16]  T row-major
    float* tslot = smem + 9216;        // [term, ti]

    if (t < 256) Trows[t] = trans[t];
    __syncthreads();

    const int G = t >> 4, r = t & 15;

    // ---- V1: compose chunk matrices P_c (lane r holds row r of P) ----
    {
      float Tcol[16];
      #pragma unroll
      for (int j = 0; j < 16; ++j) Tcol[j] = Trows[j * 16 + r];

      for (int cc = 0; cc < 2; ++cc) {
        const int c = G * 2 + cc, t0 = c * 64;
        float P[16];
        {
          const float4* fr = (const float4*)&feats[t0 * 16];
          float4 fA = fr[0], fB = fr[1], fC = fr[2], fD = fr[3];
          float ff[16];
          ff[0]=fA.x; ff[1]=fA.y; ff[2]=fA.z; ff[3]=fA.w;
          ff[4]=fB.x; ff[5]=fB.y; ff[6]=fB.z; ff[7]=fB.w;
          ff[8]=fC.x; ff[9]=fC.y; ff[10]=fC.z; ff[11]=fC.w;
          ff[12]=fD.x; ff[13]=fD.y; ff[14]=fD.z; ff[15]=fD.w;
          #pragma unroll
          for (int j = 0; j < 16; ++j) P[j] = Tcol[j] + ff[j];
        }
        for (int tt = t0 + 1; tt < t0 + 64; ++tt) {
          const float4* fr = (const float4*)&feats[tt * 16];
          float4 fA = fr[0], fB = fr[1], fC = fr[2], fD = fr[3];
          float ff[16];
          ff[0]=fA.x; ff[1]=fA.y; ff[2]=fA.z; ff[3]=fA.w;
          ff[4]=fB.x; ff[5]=fB.y; ff[6]=fB.z; ff[7]=fB.w;
          ff[8]=fC.x; ff[9]=fC.y; ff[10]=fC.z; ff[11]=fC.w;
          ff[12]=fD.x; ff[13]=fD.y; ff[14]=fD.z; ff[15]=fD.w;
          float Q[16];
          #pragma unroll
          for (int j = 0; j < 16; ++j) {
            const float4 Ta = *(const float4*)&Trows[j * 16 + 0];
            const float4 Tb = *(const float4*)&Trows[j * 16 + 4];
            const float4 Tc2 = *(const float4*)&Trows[j * 16 + 8];
            const float4 Td = *(const float4*)&Trows[j * 16 + 12];
            float m0 = fmaxf(P[0]  + Ta.x,  P[1]  + Ta.y);
            float m1 = fmaxf(P[2]  + Ta.z,  P[3]  + Ta.w);
            float m2 = fmaxf(P[4]  + Tb.x,  P[5]  + Tb.y);
            float m3 = fmaxf(P[6]  + Tb.z,  P[7]  + Tb.w);
            float m4 = fmaxf(P[8]  + Tc2.x, P[9]  + Tc2.y);
            float m5 = fmaxf(P[10] + Tc2.z, P[11] + Tc2.w);
            float m6 = fmaxf(P[12] + Td.x,  P[13] + Td.y);
            float m7 = fmaxf(P[14] + Td.z,  P[15] + Td.w);
            float m = fmaxf(fmaxf(fmaxf(m0, m1), fmaxf(m2, m3)),
                            fmaxf(fmaxf(m4, m5), fmaxf(m6, m7)));
            Q[j] = m + ff[j];
          }
          #pragma unroll
          for (int j = 0; j < 16; ++j) P[j] = Q[j];
        }
        #pragma unroll
        for (int j = 0; j < 16; ++j) P_ls[c * 256 + r * 16 + j] = P[j];
      }
    }
    __syncthreads();

    // ---- V2: boundary scan (lanes 0..15 of wave 0) ----
    if (t < 16) {
      float m = (t == 0) ? 0.0f : NEGV;   // v[-1]
      for (int c = 0; c < 32; ++c) {
        float vv[16];
        #pragma unroll
        for (int i = 0; i < 16; ++i) vv[i] = __shfl(m, i, 16);
        float nm = vv[0] + P_ls[c * 256 + 0 * 16 + t];
        #pragma unroll
        for (int i = 1; i < 16; ++i)
          nm = fmaxf(nm, vv[i] + P_ls[c * 256 + i * 16 + t]);
        vb[c * 16 + t] = nm;
        m = nm;
      }
    }
    __syncthreads();

    // ---- V3: replay chunks, write bp bytes into dead P region ----
    {
      unsigned char* bpB = (unsigned char*)P_ls;   // [2048][16] bytes = 32KB
      float Trow[16];
      #pragma unroll
      for (int k2 = 0; k2 < 16; ++k2) Trow[k2] = Trows[r * 16 + k2];

      for (int cc = 0; cc < 2; ++cc) {
        const int c = G * 2 + cc, t0 = c * 64;
        float vcur = (c == 0) ? ((r == 0) ? 0.0f : NEGV) : vb[(c - 1) * 16 + r];
        float fnext = feats[t0 * 16 + r];
        for (int tt = t0; tt < t0 + 64; ++tt) {
          float f = fnext;
          if (tt + 1 < t0 + 64) fnext = feats[(tt + 1) * 16 + r];
          float vv[16];
          #pragma unroll
          for (int i = 0; i < 16; ++i) vv[i] = __shfl(vcur, i, 16);
          float m = vv[0] + Trow[0]; int mi = 0;
          #pragma unroll
          for (int i = 1; i < 16; ++i) {
            float s2 = vv[i] + Trow[i];
            if (s2 > m) { m = s2; mi = i; }
          }
          vcur = m + f;
          bpB[tt * 16 + r] = (unsigned char)mi;
        }
      }
    }
    __syncthreads();

    // ---- V4a: terminal argmax (first-index ties) ----
    if (t < 16) {
      float term = vb[31 * 16 + t] + trans[16 + t];   // STOP row = 1
      int ti = t;
      #pragma unroll
      for (int mask = 1; mask <= 8; mask <<= 1) {
        float om = __shfl_xor(term, mask);
        int omi = __shfl_xor(ti, mask);
        if (om > term || (om == term && omi < ti)) { term = om; ti = omi; }
      }
      if (t == 0) { tslot[0] = term; tslot[1] = __int_as_float(ti); }
    }
    __syncthreads();

    // ---- V4b: map-suffix-scan backtrack (wave 0), maps from bp bytes ----
    if (t < 64) {
      const unsigned char* bpB = (const unsigned char*)P_ls;
      const int l = t;
      ull M = 0;
      {
        const int tb = 32 * l + 31;
        #pragma unroll
        for (int j = 0; j < 16; ++j)
          M |= (ull)(bpB[tb * 16 + j] & 15) << (4 * j);
      }
      for (int i = 30; i >= 0; --i) {
        const int ta = 32 * l + i;
        ull Mn = 0;
        #pragma unroll
        for (int j = 0; j < 16; ++j) {
          int idx = (int)((M >> (4 * j)) & 15);
          Mn |= (ull)(bpB[ta * 16 + idx] & 15) << (4 * j);
        }
        M = Mn;
      }
      ull Sm = M;
      #pragma unroll
      for (int d = 1; d < 64; d <<= 1) {
        ull o = __shfl_down(Sm, d);
        if (l + d < 64) Sm = compose_map(Sm, o);
      }
      ull Gm = __shfl_down(Sm, 1);
      if (l == 63) Gm = 0xFEDCBA9876543210ULL;   // identity

      int ti = __float_as_int(tslot[1]);
      int cur = (int)((Gm >> (4 * ti)) & 15);    // tag @ t = 32l+31
      for (int i = 31; i >= 1; --i) {
        int tt2 = 32 * l + i;
        out[1 + tt2] = (float)cur;
        cur = bpB[tt2 * 16 + cur] & 15;          // tag @ tt2-1
      }
      out[1 + 32 * l] = (float)cur;
      if (l == 0) out[0] = tslot[0];
    }
  }
}

extern "C" void kernel_launch(void* const* d_in, const int* in_sizes, int n_in,
                              void* d_out, int out_size, void* d_ws, size_t ws_size,
                              hipStream_t stream) {
  const int*   sent  = (const int*)d_in[0];
  const float* emb   = (const float*)d_in[1];
  const float* Wih_f = (const float*)d_in[2];
  const float* Whh_f = (const float*)d_in[3];
  const float* bih_f = (const float*)d_in[4];
  const float* bhh_f = (const float*)d_in[5];
  const float* Wih_b = (const float*)d_in[6];
  const float* Whh_b = (const float*)d_in[7];
  const float* bih_b = (const float*)d_in[8];
  const float* bhh_b = (const float*)d_in[9];
  const float* h0    = (const float*)d_in[10];
  const float* c0    = (const float*)d_in[11];
  const float* Wout  = (const float*)d_in[12];
  const float* bout  = (const float*)d_in[13];
  const float* trans = (const float*)d_in[14];
  float* out = (float*)d_out;

  // workspace layout
  char* ws = (char*)d_ws;
  float* xg     = (float*)(ws);                         // 2048*4096*4 = 32 MiB
  float* hs_cat = (float*)(ws + 33554432);              // 2048*1024*4 = 8 MiB
  float* feats  = (float*)(ws + 41943040);              // 2048*16*4 = 128 KiB
  ull*   hbuf   = (ull*)  (ws + 42074112);              // 2*2*512*8 = 16 KiB
  int*   flags  = (int*)  (ws + 42090496);              // 2048 tile flags + 2 counters

  init_k<<<6, 512, 0, stream>>>(h0, hbuf, flags);
  fused_k<<<256, 256, 0, stream>>>(sent, emb, Wih_f, Wih_b, bih_f, bhh_f,
                                   bih_b, bhh_b, Whh_f, Whh_b, c0, Wout, bout,
                                   trans, xg, hbuf, hs_cat, feats, flags, out);
}